// Round 1
// baseline (543.300 us; speedup 1.0000x reference)
//
#include <hip/hip_runtime.h>

typedef unsigned short u16;
typedef __attribute__((ext_vector_type(8))) short short8;
typedef __attribute__((ext_vector_type(4))) float f32x4;
typedef __attribute__((ext_vector_type(4))) unsigned short u16x4;

// ---------- bf16 helpers (OCP bf16 = raw upper 16 bits of fp32, RNE) ----------
__device__ __forceinline__ float bf2f(u16 h){
  unsigned u = ((unsigned)h) << 16; float f; __builtin_memcpy(&f, &u, 4); return f;
}
__device__ __forceinline__ u16 f2bf(float f){
  unsigned u; __builtin_memcpy(&u, &f, 4);
  unsigned r = u + 0x7fffu + ((u >> 16) & 1u);
  return (u16)(r >> 16);
}

// ---------- async global->LDS (16B per lane, wave-uniform LDS base) ----------
__device__ __forceinline__ void glds16(const u16* g, u16* l){
  __builtin_amdgcn_global_load_lds(
      (const __attribute__((address_space(1))) unsigned int*)(const void*)g,
      (__attribute__((address_space(3))) unsigned int*)(void*)l, 16, 0, 0);
}

// ---------- fused fp32 -> bf16 conversion: x (8192 blocks) + 4 weights ----------
__global__ __launch_bounds__(256) void cvt_all(const float* __restrict__ x,
    const float* __restrict__ w0, const float* __restrict__ w1,
    const float* __restrict__ w2, const float* __restrict__ w3,
    u16* __restrict__ xb, u16* __restrict__ wb){
  int blk = blockIdx.x;
  const float* src; u16* dst; int i;
  if (blk < 8192){
    src = x; dst = xb; i = blk * 256 + threadIdx.x;
  } else {
    int b2 = blk - 8192;
    int which = b2 >> 12;
    src = (which == 0) ? w0 : (which == 1) ? w1 : (which == 2) ? w2 : w3;
    dst = wb + (size_t)which * 4194304;
    i = (b2 & 4095) * 256 + threadIdx.x;
  }
  float4 f = ((const float4*)src)[i];
  u16x4 o; o.x = f2bf(f.x); o.y = f2bf(f.y); o.z = f2bf(f.z); o.w = f2bf(f.w);
  ((u16x4*)dst)[i] = o;
}

// ---------- GEMM C[M,N] = A[M,K] @ B[N,K]^T  (both bf16, K=2048, BK=64) ----------
// m97-exact structure: 128x128 tile, BK=64, width-16 global_load_lds, XOR-swizzled
// zero-conflict LDS, 32 MFMA per barrier pair (was 16 at BK=32). Fused bias+RoPE
// epilogue unchanged.
__global__ __launch_bounds__(256) void gemm_bt(
    const u16* __restrict__ A, const u16* __restrict__ Bm, int mode,
    u16* __restrict__ qws, u16* __restrict__ kws, u16* __restrict__ vws,
    const float* __restrict__ bq, const float* __restrict__ bk, const float* __restrict__ bv,
    float* __restrict__ outf, const float* __restrict__ bo)
{
  const int K = 2048;
  __shared__ __attribute__((aligned(16))) u16 As[128 * 64];   // 16 KB
  __shared__ __attribute__((aligned(16))) u16 Bs[128 * 64];   // 16 KB

  int tid = threadIdx.x, wave = tid >> 6, lane = tid & 63;
  int quad = lane >> 4, l15 = lane & 15;
  int wm = wave >> 1, wn = wave & 1;

  size_t rowA0 = (size_t)blockIdx.y * 128;
  size_t rowB0 = (size_t)blockIdx.x * 128;

  // Staging geometry: LDS granule s (16B) = ri*256 + wave*64 + lane holds
  // global (row = s>>3, k-granule = (s&7) ^ (row&7)).  glds dest is linear in
  // lane (HW requirement); the swizzle lives in the per-lane GLOBAL address.
  const u16* gA[4]; const u16* gB[4]; u16* lA[4]; u16* lB[4];
  #pragma unroll
  for (int ri = 0; ri < 4; ri++){
    int s = ri * 256 + tid;
    int lrow = s >> 3, p = s & 7;
    int c = p ^ (lrow & 7);
    gA[ri] = A  + (rowA0 + lrow) * K + c * 8;
    gB[ri] = Bm + (rowB0 + lrow) * K + c * 8;
    lA[ri] = As + (size_t)(ri * 256 + wave * 64) * 8;
    lB[ri] = Bs + (size_t)(ri * 256 + wave * 64) * 8;
  }

  f32x4 acc[4][4];
  #pragma unroll
  for (int i = 0; i < 4; i++)
    #pragma unroll
    for (int j = 0; j < 4; j++) acc[i][j] = f32x4{0.f, 0.f, 0.f, 0.f};

  // Read offsets: fragment (row r, k-half kk) lives at granule
  // r*8 + ((kk*4+quad) ^ (r&7)); 8 slots x 128B rows spread uniformly over all
  // 32 banks (8 lanes per 16B slot = the b128 minimum, zero extra conflict).
  int aoff[4][2], boff[4][2];
  #pragma unroll
  for (int t = 0; t < 4; t++){
    int ra = wm * 64 + t * 16 + l15;
    int rb = wn * 32 + (t >> 1) * 64 + (t & 1) * 16 + l15;
    #pragma unroll
    for (int kk = 0; kk < 2; kk++){
      aoff[t][kk] = ra * 64 + (((kk * 4 + quad) ^ (ra & 7)) * 8);
      boff[t][kk] = rb * 64 + (((kk * 4 + quad) ^ (rb & 7)) * 8);
    }
  }

  for (int k0 = 0; k0 < K; k0 += 64){
    __syncthreads();
    #pragma unroll
    for (int ri = 0; ri < 4; ri++){
      glds16(gA[ri], lA[ri]);
      glds16(gB[ri], lB[ri]);
    }
    #pragma unroll
    for (int ri = 0; ri < 4; ri++){ gA[ri] += 64; gB[ri] += 64; }
    __syncthreads();
    #pragma unroll
    for (int kk = 0; kk < 2; kk++){
      short8 af[4], bfr[4];
      #pragma unroll
      for (int t = 0; t < 4; t++){
        af[t]  = *(const short8*)(As + aoff[t][kk]);
        bfr[t] = *(const short8*)(Bs + boff[t][kk]);
      }
      #pragma unroll
      for (int i = 0; i < 4; i++)
        #pragma unroll
        for (int j = 0; j < 4; j++)
          acc[i][j] = __builtin_amdgcn_mfma_f32_16x16x32_bf16(af[i], bfr[j], acc[i][j], 0, 0, 0);
    }
  }

  if (mode == 0){
    int col0 = (int)rowB0;
    int mat = col0 >> 11;                  // 0=Q 1=K 2=V
    int cm  = col0 & 2047;
    const float* bias = (mat == 0) ? bq : (mat == 1) ? bk : bv;
    int b  = (int)(rowA0 >> 11);
    int s0 = (int)(rowA0 & 2047);
    int h  = cm >> 7;
    size_t base = ((size_t)(b * 16 + h)) * 2048 * 128;
    if (mat == 2){
      // V stored TRANSPOSED: [B,H,DK,S]
      #pragma unroll
      for (int j = 0; j < 4; j++){
        int d = wn * 32 + (j >> 1) * 64 + (j & 1) * 16 + l15;
        float bv_ = bias[cm + d];
        #pragma unroll
        for (int i = 0; i < 4; i++){
          int srow = s0 + wm * 64 + i * 16 + quad * 4;
          u16x4 pk;
          #pragma unroll
          for (int r = 0; r < 4; r++) pk[r] = f2bf(acc[i][j][r] + bv_);
          *(u16x4*)(vws + base + (size_t)d * 2048 + srow) = pk;
        }
      }
    } else {
      // Q/K: fused bias + RoPE, pairs (dlow, dlow+64) = (acc[*][jp], acc[*][jp+2])
      u16* dst = (mat == 0) ? qws : kws;
      #pragma unroll
      for (int jp = 0; jp < 2; jp++){
        int dlow = wn * 32 + jp * 16 + l15;          // 0..63
        float bias_lo = bias[cm + dlow];
        float bias_hi = bias[cm + dlow + 64];
        float invf = __expf(-0.14391156831212788f * (float)dlow);
        #pragma unroll
        for (int i = 0; i < 4; i++){
          int srow0 = s0 + wm * 64 + i * 16 + quad * 4;
          #pragma unroll
          for (int r = 0; r < 4; r++){
            float a  = acc[i][jp][r]     + bias_lo;
            float b2 = acc[i][jp + 2][r] + bias_hi;
            float th = (float)(srow0 + r) * invf;
            float sn, cs; __sincosf(th, &sn, &cs);
            size_t ro = base + (size_t)(srow0 + r) * 128;
            dst[ro + dlow]      = f2bf(a * cs - b2 * sn);
            dst[ro + dlow + 64] = f2bf(b2 * cs + a * sn);
          }
        }
      }
    }
  } else {
    int col0 = (int)rowB0;
    #pragma unroll
    for (int j = 0; j < 4; j++){
      int c = col0 + wn * 32 + (j >> 1) * 64 + (j & 1) * 16 + l15;
      float bo_ = bo[c];
      #pragma unroll
      for (int i = 0; i < 4; i++){
        int rg = (int)rowA0 + wm * 64 + i * 16 + quad * 4;
        #pragma unroll
        for (int r = 0; r < 4; r++)
          outf[(size_t)(rg + r) * 2048 + c] = acc[i][j][r] + bo_;
      }
    }
  }
}

// ---------- causal flash attention: balanced pairs + double-buffered staging ----------
// grid (8, 32 bh); block = 4 waves, 1 block/CU (82 KB LDS). Block pr handles q-tiles
// pr and 15-pr sequentially -> every block = exactly 34 kv-iters of 64. K/V staged
// into LDS[2] ping-pong via glds16; prefetch for iter it+1 issued right after the
// iter-it barrier so the vmcnt(0) drain at the next barrier is already satisfied.
__global__ __launch_bounds__(256) void flash(
    const u16* __restrict__ Q, const u16* __restrict__ Km, const u16* __restrict__ VT,
    u16* __restrict__ O)
{
  __shared__ __attribute__((aligned(16))) u16 Ks[2][64 * 128];  // 2x16 KB
  __shared__ __attribute__((aligned(16))) u16 Vs[2][128 * 64];  // 2x16 KB (V^T: [d][kv])
  __shared__ __attribute__((aligned(16))) u16 PL[4 * 32 * 72];  // 18 KB per-wave P
  const float scale = 0.08838834764831845f;   // 1/sqrt(128)

  int bh = blockIdx.y;
  int pr = (int)blockIdx.x;              // 0..7
  int tid = threadIdx.x, wave = tid >> 6, lane = tid & 63;
  int quad = lane >> 4, l15 = lane & 15;

  const u16* Qb = Q  + (size_t)bh * 2048 * 128;
  const u16* Kb = Km + (size_t)bh * 2048 * 128;
  const u16* Vb = VT + (size_t)bh * 2048 * 128;   // [d=128][s=2048]
  u16* PW = PL + wave * (32 * 72);

  // staging lane geometry (tile-relative)
  const u16* gKb[4]; const u16* gVb[4]; int lOff[4];
  #pragma unroll
  for (int r = 0; r < 4; r++){
    int ci = r * 256 + wave * 64 + lane;
    int krow = ci >> 4;
    int klog = (ci & 15) ^ (krow & 15);
    gKb[r] = Kb + (size_t)krow * 128 + klog * 8;   // + k0*128 per tile
    int vd = ci >> 3;
    int vlog = (ci & 7) ^ (vd & 7);
    gVb[r] = Vb + (size_t)vd * 2048 + vlog * 8;    // + k0 per tile
    lOff[r] = (r * 256 + wave * 64) * 8;
  }

  for (int phase = 0; phase < 2; phase++){
    int qtile = phase ? (15 - pr) : pr;
    int qw = qtile * 128 + wave * 32;

    short8 qf[2][4];
    #pragma unroll
    for (int m = 0; m < 2; m++){
      const u16* qr = Qb + (size_t)(qw + m * 16 + l15) * 128 + quad * 8;
      #pragma unroll
      for (int c = 0; c < 4; c++) qf[m][c] = *(const short8*)(qr + c * 32);
    }

    float mr[2][4], lr[2][4]; f32x4 o[2][8];
    #pragma unroll
    for (int m = 0; m < 2; m++)
      #pragma unroll
      for (int r = 0; r < 4; r++){ mr[m][r] = -1e30f; lr[m][r] = 0.f; }
    #pragma unroll
    for (int m = 0; m < 2; m++)
      #pragma unroll
      for (int blk = 0; blk < 8; blk++) o[m][blk] = f32x4{0.f, 0.f, 0.f, 0.f};

    int niter = (qtile + 1) * 2;

    __syncthreads();   // previous phase's reads of Ks/Vs complete before re-staging
    #pragma unroll
    for (int r = 0; r < 4; r++){
      glds16(gKb[r], Ks[0] + lOff[r]);
      glds16(gVb[r], Vs[0] + lOff[r]);
    }

    for (int it = 0; it < niter; it++){
      int k0 = it * 64;
      int buf = it & 1;
      __syncthreads();   // vmcnt(0)+barrier: buf's tile landed; all waves done w/ buf^1
      if (it + 1 < niter){
        int nb = buf ^ 1;
        #pragma unroll
        for (int r = 0; r < 4; r++){
          glds16(gKb[r] + (size_t)(k0 + 64) * 128, Ks[nb] + lOff[r]);
          glds16(gVb[r] + (k0 + 64),               Vs[nb] + lOff[r]);
        }
      }
      const u16* KsB = Ks[buf];
      const u16* VsB = Vs[buf];

      int rel = qw + 31 - k0;
      if (rel >= 0){
        int smax = rel >> 4; if (smax > 3) smax = 3;
        float sreg[2][4][4];
        #pragma unroll
        for (int t = 0; t < 4; t++){
          if (t <= smax){
            short8 kf[4];
            #pragma unroll
            for (int c = 0; c < 4; c++)
              kf[c] = *(const short8*)(KsB + (t * 16 + l15) * 128 + (((c * 4 + quad) ^ l15) * 8));
            #pragma unroll
            for (int m = 0; m < 2; m++){
              f32x4 a = f32x4{0.f, 0.f, 0.f, 0.f};
              #pragma unroll
              for (int c = 0; c < 4; c++)
                a = __builtin_amdgcn_mfma_f32_16x16x32_bf16(qf[m][c], kf[c], a, 0, 0, 0);
              int kvcol = k0 + t * 16 + l15;
              #pragma unroll
              for (int r = 0; r < 4; r++){
                float v = a[r] * scale;
                int row = qw + m * 16 + quad * 4 + r;
                if (kvcol > row) v = -1e30f;
                sreg[m][t][r] = v;
              }
            }
          }
        }
        float alpha[2][4];
        #pragma unroll
        for (int m = 0; m < 2; m++){
          #pragma unroll
          for (int r = 0; r < 4; r++){
            float x = sreg[m][0][r];
            #pragma unroll
            for (int t = 1; t < 4; t++) if (t <= smax) x = fmaxf(x, sreg[m][t][r]);
            x = fmaxf(x, __shfl_xor(x, 1));
            x = fmaxf(x, __shfl_xor(x, 2));
            x = fmaxf(x, __shfl_xor(x, 4));
            x = fmaxf(x, __shfl_xor(x, 8));
            float mn = fmaxf(mr[m][r], x);
            alpha[m][r] = __expf(mr[m][r] - mn);
            mr[m][r] = mn;
          }
        }
        float lsum[2][4];
        #pragma unroll
        for (int m = 0; m < 2; m++)
          #pragma unroll
          for (int r = 0; r < 4; r++) lsum[m][r] = 0.f;
        #pragma unroll
        for (int t = 0; t < 4; t++){
          if (t <= smax){
            #pragma unroll
            for (int m = 0; m < 2; m++)
              #pragma unroll
              for (int r = 0; r < 4; r++){
                float p = __expf(sreg[m][t][r] - mr[m][r]);
                lsum[m][r] += p;
                PW[(m * 16 + quad * 4 + r) * 72 + t * 16 + l15] = f2bf(p);
              }
          }
        }
        if (!(smax & 1)){
          #pragma unroll
          for (int m = 0; m < 2; m++)
            #pragma unroll
            for (int r = 0; r < 4; r++)
              PW[(m * 16 + quad * 4 + r) * 72 + (smax + 1) * 16 + l15] = 0;
        }
        #pragma unroll
        for (int m = 0; m < 2; m++)
          #pragma unroll
          for (int r = 0; r < 4; r++){
            float sv = lsum[m][r];
            sv += __shfl_xor(sv, 1); sv += __shfl_xor(sv, 2);
            sv += __shfl_xor(sv, 4); sv += __shfl_xor(sv, 8);
            lr[m][r] = lr[m][r] * alpha[m][r] + sv;
          }
        #pragma unroll
        for (int m = 0; m < 2; m++)
          #pragma unroll
          for (int blk = 0; blk < 8; blk++){
            o[m][blk][0] *= alpha[m][0]; o[m][blk][1] *= alpha[m][1];
            o[m][blk][2] *= alpha[m][2]; o[m][blk][3] *= alpha[m][3];
          }
        __builtin_amdgcn_s_waitcnt(0xC07F);   // lgkmcnt(0): own-wave P writes visible
        int nch = (smax >> 1) + 1;
        #pragma unroll
        for (int c2 = 0; c2 < 2; c2++){
          if (c2 < nch){
            short8 pf[2];
            #pragma unroll
            for (int m = 0; m < 2; m++)
              pf[m] = *(const short8*)(PW + (m * 16 + l15) * 72 + c2 * 32 + quad * 8);
            #pragma unroll
            for (int blk = 0; blk < 8; blk++){
              int d = blk * 16 + l15;
              short8 vf = *(const short8*)(VsB + d * 64 + (((c2 * 4 + quad) ^ (l15 & 7)) * 8));
              #pragma unroll
              for (int m = 0; m < 2; m++)
                o[m][blk] = __builtin_amdgcn_mfma_f32_16x16x32_bf16(pf[m], vf, o[m][blk], 0, 0, 0);
            }
          }
        }
      }
    }

    // phase epilogue
    int b = bh >> 4, h = bh & 15;
    #pragma unroll
    for (int m = 0; m < 2; m++){
      float inv[4];
      #pragma unroll
      for (int r = 0; r < 4; r++) inv[r] = 1.0f / lr[m][r];
      #pragma unroll
      for (int blk = 0; blk < 8; blk++){
        int d = h * 128 + blk * 16 + l15;
        #pragma unroll
        for (int r = 0; r < 4; r++){
          int srow = qw + m * 16 + quad * 4 + r;
          O[((size_t)(b * 2048 + srow)) * 2048 + d] = f2bf(o[m][blk][r] * inv[r]);
        }
      }
    }
  }
}

// ---------- launcher ----------
extern "C" void kernel_launch(void* const* d_in, const int* in_sizes, int n_in,
                              void* d_out, int out_size, void* d_ws, size_t ws_size,
                              hipStream_t stream)
{
  const float* x  = (const float*)d_in[0];
  const float* Wq = (const float*)d_in[2];
  const float* bq = (const float*)d_in[3];
  const float* Wk = (const float*)d_in[4];
  const float* bk = (const float*)d_in[5];
  const float* Wv = (const float*)d_in[6];
  const float* bv = (const float*)d_in[7];
  const float* Wo = (const float*)d_in[8];
  const float* bo = (const float*)d_in[9];
  float* out = (float*)d_out;

  char* ws = (char*)d_ws;
  u16* xb   = (u16*)(ws);                    // [4096][2048]
  u16* wcat = (u16*)(ws + 16777216);         // [6144][2048] Wq|Wk|Wv, Wo contiguous after
  u16* wob  = (u16*)(ws + 41943040);         // [2048][2048]
  u16* qws  = (u16*)(ws + 50331648);         // [32][2048][128]
  u16* kws  = (u16*)(ws + 67108864);
  u16* vws  = (u16*)(ws + 83886080);         // [32][128][2048] V^T
  u16* attn = (u16*)(ws + 100663296);        // [4096][2048]

  cvt_all<<<24576, 256, 0, stream>>>(x, Wq, Wk, Wv, Wo, xb, wcat);

  gemm_bt<<<dim3(48, 32), 256, 0, stream>>>(xb, wcat, 0, qws, kws, vws,
                                            bq, bk, bv, nullptr, nullptr);
  flash<<<dim3(8, 32), 256, 0, stream>>>(qws, kws, vws, attn);
  gemm_bt<<<dim3(16, 32), 256, 0, stream>>>(attn, wob, 1, nullptr, nullptr, nullptr,
                                            nullptr, nullptr, nullptr, out, bo);
}

// Round 2
// 417.732 us; speedup vs baseline: 1.3006x; 1.3006x over previous
//
#include <hip/hip_runtime.h>

typedef unsigned short u16;
typedef __attribute__((ext_vector_type(8))) short short8;
typedef __attribute__((ext_vector_type(4))) float f32x4;
typedef __attribute__((ext_vector_type(4))) unsigned short u16x4;

// ---------- bf16 helpers (OCP bf16 = raw upper 16 bits of fp32, RNE) ----------
__device__ __forceinline__ float bf2f(u16 h){
  unsigned u = ((unsigned)h) << 16; float f; __builtin_memcpy(&f, &u, 4); return f;
}
__device__ __forceinline__ u16 f2bf(float f){
  unsigned u; __builtin_memcpy(&u, &f, 4);
  unsigned r = u + 0x7fffu + ((u >> 16) & 1u);
  return (u16)(r >> 16);
}

// ---------- async global->LDS (16B per lane, wave-uniform LDS base) ----------
__device__ __forceinline__ void glds16(const u16* g, u16* l){
  __builtin_amdgcn_global_load_lds(
      (const __attribute__((address_space(1))) unsigned int*)(const void*)g,
      (__attribute__((address_space(3))) unsigned int*)(void*)l, 16, 0, 0);
}

// ---------- fused fp32 -> bf16 conversion: x (8192 blocks) + 4 weights ----------
__global__ __launch_bounds__(256) void cvt_all(const float* __restrict__ x,
    const float* __restrict__ w0, const float* __restrict__ w1,
    const float* __restrict__ w2, const float* __restrict__ w3,
    u16* __restrict__ xb, u16* __restrict__ wb){
  int blk = blockIdx.x;
  const float* src; u16* dst; int i;
  if (blk < 8192){
    src = x; dst = xb; i = blk * 256 + threadIdx.x;
  } else {
    int b2 = blk - 8192;
    int which = b2 >> 12;
    src = (which == 0) ? w0 : (which == 1) ? w1 : (which == 2) ? w2 : w3;
    dst = wb + (size_t)which * 4194304;
    i = (b2 & 4095) * 256 + threadIdx.x;
  }
  float4 f = ((const float4*)src)[i];
  u16x4 o; o.x = f2bf(f.x); o.y = f2bf(f.y); o.z = f2bf(f.z); o.w = f2bf(f.w);
  ((u16x4*)dst)[i] = o;
}

// ---------- GEMM C[M,N] = A[M,K] @ B[N,K]^T  (both bf16, K=2048, BK=64) ----------
// BK=64 (32 MFMA per barrier pair) with register diet to stay under the 128-VGPR
// occupancy cliff (m69: waves/CU halve at 128): 2 staging pointers instead of 8
// (ri-offset is a compile-time +ri*32*K; swizzle k-granule is ri-invariant since
// 32%8==0), and kk=1 LDS read offsets derived via ^32 ((x^4)<<3 == (x<<3)^32).
// __launch_bounds__(256,4) pins the allocator to <=128 VGPR -> 4 blocks/CU.
__global__ __launch_bounds__(256, 4) void gemm_bt(
    const u16* __restrict__ A, const u16* __restrict__ Bm, int mode,
    u16* __restrict__ qws, u16* __restrict__ kws, u16* __restrict__ vws,
    const float* __restrict__ bq, const float* __restrict__ bk, const float* __restrict__ bv,
    float* __restrict__ outf, const float* __restrict__ bo)
{
  const int K = 2048;
  __shared__ __attribute__((aligned(16))) u16 As[128 * 64];   // 16 KB
  __shared__ __attribute__((aligned(16))) u16 Bs[128 * 64];   // 16 KB

  int tid = threadIdx.x, wave = tid >> 6, lane = tid & 63;
  int quad = lane >> 4, l15 = lane & 15;
  int wm = wave >> 1, wn = wave & 1;

  size_t rowA0 = (size_t)blockIdx.y * 128;
  size_t rowB0 = (size_t)blockIdx.x * 128;

  // Staging geometry: LDS granule s (16B) = ri*256 + tid holds global
  // (row = s>>3, k-granule = (s&7) ^ (row&7)). ri*256 is 0 mod 8, and
  // ri*32 rows is 0 mod 8, so both (s&7) and (row&7) are ri-invariant:
  // one base pointer + constant ri*32*K offset suffices.
  int lrow0 = tid >> 3;
  int c0 = (tid & 7) ^ (lrow0 & 7);
  const u16* gA = A  + (rowA0 + lrow0) * K + c0 * 8;
  const u16* gB = Bm + (rowB0 + lrow0) * K + c0 * 8;
  u16* lA = As + (size_t)(wave * 64) * 8;
  u16* lB = Bs + (size_t)(wave * 64) * 8;

  f32x4 acc[4][4];
  #pragma unroll
  for (int i = 0; i < 4; i++)
    #pragma unroll
    for (int j = 0; j < 4; j++) acc[i][j] = f32x4{0.f, 0.f, 0.f, 0.f};

  // Read offsets (elements): fragment (row r, k-granule kg) lives at
  // r*64 + ((kg ^ (r&7))*8). kk=0 -> kg=quad; kk=1 -> kg=4+quad = quad^4,
  // so the kk=1 offset is the kk=0 offset ^ 32.
  int aoff[4], boff[4];
  #pragma unroll
  for (int t = 0; t < 4; t++){
    int ra = wm * 64 + t * 16 + l15;
    aoff[t] = ra * 64 + ((quad ^ (ra & 7)) * 8);
    int rb = wn * 32 + (t >> 1) * 64 + (t & 1) * 16 + l15;
    boff[t] = rb * 64 + ((quad ^ (rb & 7)) * 8);
  }

  for (int k0 = 0; k0 < K; k0 += 64){
    __syncthreads();
    #pragma unroll
    for (int ri = 0; ri < 4; ri++){
      glds16(gA + ri * 65536, lA + ri * 2048);   // ri*32 rows * K elements
      glds16(gB + ri * 65536, lB + ri * 2048);
    }
    gA += 64; gB += 64;
    __syncthreads();
    #pragma unroll
    for (int kk = 0; kk < 2; kk++){
      const int kx = kk * 32;
      short8 af[4], bfr[4];
      #pragma unroll
      for (int t = 0; t < 4; t++){
        af[t]  = *(const short8*)(As + (aoff[t] ^ kx));
        bfr[t] = *(const short8*)(Bs + (boff[t] ^ kx));
      }
      #pragma unroll
      for (int i = 0; i < 4; i++)
        #pragma unroll
        for (int j = 0; j < 4; j++)
          acc[i][j] = __builtin_amdgcn_mfma_f32_16x16x32_bf16(af[i], bfr[j], acc[i][j], 0, 0, 0);
    }
  }

  if (mode == 0){
    int col0 = (int)rowB0;
    int mat = col0 >> 11;                  // 0=Q 1=K 2=V
    int cm  = col0 & 2047;
    const float* bias = (mat == 0) ? bq : (mat == 1) ? bk : bv;
    int b  = (int)(rowA0 >> 11);
    int s0 = (int)(rowA0 & 2047);
    int h  = cm >> 7;
    size_t base = ((size_t)(b * 16 + h)) * 2048 * 128;
    if (mat == 2){
      // V stored TRANSPOSED: [B,H,DK,S]
      #pragma unroll
      for (int j = 0; j < 4; j++){
        int d = wn * 32 + (j >> 1) * 64 + (j & 1) * 16 + l15;
        float bv_ = bias[cm + d];
        #pragma unroll
        for (int i = 0; i < 4; i++){
          int srow = s0 + wm * 64 + i * 16 + quad * 4;
          u16x4 pk;
          #pragma unroll
          for (int r = 0; r < 4; r++) pk[r] = f2bf(acc[i][j][r] + bv_);
          *(u16x4*)(vws + base + (size_t)d * 2048 + srow) = pk;
        }
      }
    } else {
      // Q/K: fused bias + RoPE, pairs (dlow, dlow+64) = (acc[*][jp], acc[*][jp+2])
      u16* dst = (mat == 0) ? qws : kws;
      #pragma unroll
      for (int jp = 0; jp < 2; jp++){
        int dlow = wn * 32 + jp * 16 + l15;          // 0..63
        float bias_lo = bias[cm + dlow];
        float bias_hi = bias[cm + dlow + 64];
        float invf = __expf(-0.14391156831212788f * (float)dlow);
        #pragma unroll
        for (int i = 0; i < 4; i++){
          int srow0 = s0 + wm * 64 + i * 16 + quad * 4;
          #pragma unroll
          for (int r = 0; r < 4; r++){
            float a  = acc[i][jp][r]     + bias_lo;
            float b2 = acc[i][jp + 2][r] + bias_hi;
            float th = (float)(srow0 + r) * invf;
            float sn, cs; __sincosf(th, &sn, &cs);
            size_t ro = base + (size_t)(srow0 + r) * 128;
            dst[ro + dlow]      = f2bf(a * cs - b2 * sn);
            dst[ro + dlow + 64] = f2bf(b2 * cs + a * sn);
          }
        }
      }
    }
  } else {
    int col0 = (int)rowB0;
    #pragma unroll
    for (int j = 0; j < 4; j++){
      int c = col0 + wn * 32 + (j >> 1) * 64 + (j & 1) * 16 + l15;
      float bo_ = bo[c];
      #pragma unroll
      for (int i = 0; i < 4; i++){
        int rg = (int)rowA0 + wm * 64 + i * 16 + quad * 4;
        #pragma unroll
        for (int r = 0; r < 4; r++)
          outf[(size_t)(rg + r) * 2048 + c] = acc[i][j][r] + bo_;
      }
    }
  }
}

// ---------- causal flash attention: balanced pairs + double-buffered staging ----------
// grid (8, 32 bh); block = 4 waves, 1 block/CU (82 KB LDS). Block pr handles q-tiles
// pr and 15-pr sequentially -> every block = exactly 34 kv-iters of 64. K/V staged
// into LDS[2] ping-pong via glds16; prefetch for iter it+1 issued right after the
// iter-it barrier so the vmcnt(0) drain at the next barrier is already satisfied.
__global__ __launch_bounds__(256) void flash(
    const u16* __restrict__ Q, const u16* __restrict__ Km, const u16* __restrict__ VT,
    u16* __restrict__ O)
{
  __shared__ __attribute__((aligned(16))) u16 Ks[2][64 * 128];  // 2x16 KB
  __shared__ __attribute__((aligned(16))) u16 Vs[2][128 * 64];  // 2x16 KB (V^T: [d][kv])
  __shared__ __attribute__((aligned(16))) u16 PL[4 * 32 * 72];  // 18 KB per-wave P
  const float scale = 0.08838834764831845f;   // 1/sqrt(128)

  int bh = blockIdx.y;
  int pr = (int)blockIdx.x;              // 0..7
  int tid = threadIdx.x, wave = tid >> 6, lane = tid & 63;
  int quad = lane >> 4, l15 = lane & 15;

  const u16* Qb = Q  + (size_t)bh * 2048 * 128;
  const u16* Kb = Km + (size_t)bh * 2048 * 128;
  const u16* Vb = VT + (size_t)bh * 2048 * 128;   // [d=128][s=2048]
  u16* PW = PL + wave * (32 * 72);

  // staging lane geometry (tile-relative)
  const u16* gKb[4]; const u16* gVb[4]; int lOff[4];
  #pragma unroll
  for (int r = 0; r < 4; r++){
    int ci = r * 256 + wave * 64 + lane;
    int krow = ci >> 4;
    int klog = (ci & 15) ^ (krow & 15);
    gKb[r] = Kb + (size_t)krow * 128 + klog * 8;   // + k0*128 per tile
    int vd = ci >> 3;
    int vlog = (ci & 7) ^ (vd & 7);
    gVb[r] = Vb + (size_t)vd * 2048 + vlog * 8;    // + k0 per tile
    lOff[r] = (r * 256 + wave * 64) * 8;
  }

  for (int phase = 0; phase < 2; phase++){
    int qtile = phase ? (15 - pr) : pr;
    int qw = qtile * 128 + wave * 32;

    short8 qf[2][4];
    #pragma unroll
    for (int m = 0; m < 2; m++){
      const u16* qr = Qb + (size_t)(qw + m * 16 + l15) * 128 + quad * 8;
      #pragma unroll
      for (int c = 0; c < 4; c++) qf[m][c] = *(const short8*)(qr + c * 32);
    }

    float mr[2][4], lr[2][4]; f32x4 o[2][8];
    #pragma unroll
    for (int m = 0; m < 2; m++)
      #pragma unroll
      for (int r = 0; r < 4; r++){ mr[m][r] = -1e30f; lr[m][r] = 0.f; }
    #pragma unroll
    for (int m = 0; m < 2; m++)
      #pragma unroll
      for (int blk = 0; blk < 8; blk++) o[m][blk] = f32x4{0.f, 0.f, 0.f, 0.f};

    int niter = (qtile + 1) * 2;

    __syncthreads();   // previous phase's reads of Ks/Vs complete before re-staging
    #pragma unroll
    for (int r = 0; r < 4; r++){
      glds16(gKb[r], Ks[0] + lOff[r]);
      glds16(gVb[r], Vs[0] + lOff[r]);
    }

    for (int it = 0; it < niter; it++){
      int k0 = it * 64;
      int buf = it & 1;
      __syncthreads();   // vmcnt(0)+barrier: buf's tile landed; all waves done w/ buf^1
      if (it + 1 < niter){
        int nb = buf ^ 1;
        #pragma unroll
        for (int r = 0; r < 4; r++){
          glds16(gKb[r] + (size_t)(k0 + 64) * 128, Ks[nb] + lOff[r]);
          glds16(gVb[r] + (k0 + 64),               Vs[nb] + lOff[r]);
        }
      }
      const u16* KsB = Ks[buf];
      const u16* VsB = Vs[buf];

      int rel = qw + 31 - k0;
      if (rel >= 0){
        int smax = rel >> 4; if (smax > 3) smax = 3;
        float sreg[2][4][4];
        #pragma unroll
        for (int t = 0; t < 4; t++){
          if (t <= smax){
            short8 kf[4];
            #pragma unroll
            for (int c = 0; c < 4; c++)
              kf[c] = *(const short8*)(KsB + (t * 16 + l15) * 128 + (((c * 4 + quad) ^ l15) * 8));
            #pragma unroll
            for (int m = 0; m < 2; m++){
              f32x4 a = f32x4{0.f, 0.f, 0.f, 0.f};
              #pragma unroll
              for (int c = 0; c < 4; c++)
                a = __builtin_amdgcn_mfma_f32_16x16x32_bf16(qf[m][c], kf[c], a, 0, 0, 0);
              int kvcol = k0 + t * 16 + l15;
              #pragma unroll
              for (int r = 0; r < 4; r++){
                float v = a[r] * scale;
                int row = qw + m * 16 + quad * 4 + r;
                if (kvcol > row) v = -1e30f;
                sreg[m][t][r] = v;
              }
            }
          }
        }
        float alpha[2][4];
        #pragma unroll
        for (int m = 0; m < 2; m++){
          #pragma unroll
          for (int r = 0; r < 4; r++){
            float x = sreg[m][0][r];
            #pragma unroll
            for (int t = 1; t < 4; t++) if (t <= smax) x = fmaxf(x, sreg[m][t][r]);
            x = fmaxf(x, __shfl_xor(x, 1));
            x = fmaxf(x, __shfl_xor(x, 2));
            x = fmaxf(x, __shfl_xor(x, 4));
            x = fmaxf(x, __shfl_xor(x, 8));
            float mn = fmaxf(mr[m][r], x);
            alpha[m][r] = __expf(mr[m][r] - mn);
            mr[m][r] = mn;
          }
        }
        float lsum[2][4];
        #pragma unroll
        for (int m = 0; m < 2; m++)
          #pragma unroll
          for (int r = 0; r < 4; r++) lsum[m][r] = 0.f;
        #pragma unroll
        for (int t = 0; t < 4; t++){
          if (t <= smax){
            #pragma unroll
            for (int m = 0; m < 2; m++)
              #pragma unroll
              for (int r = 0; r < 4; r++){
                float p = __expf(sreg[m][t][r] - mr[m][r]);
                lsum[m][r] += p;
                PW[(m * 16 + quad * 4 + r) * 72 + t * 16 + l15] = f2bf(p);
              }
          }
        }
        if (!(smax & 1)){
          #pragma unroll
          for (int m = 0; m < 2; m++)
            #pragma unroll
            for (int r = 0; r < 4; r++)
              PW[(m * 16 + quad * 4 + r) * 72 + (smax + 1) * 16 + l15] = 0;
        }
        #pragma unroll
        for (int m = 0; m < 2; m++)
          #pragma unroll
          for (int r = 0; r < 4; r++){
            float sv = lsum[m][r];
            sv += __shfl_xor(sv, 1); sv += __shfl_xor(sv, 2);
            sv += __shfl_xor(sv, 4); sv += __shfl_xor(sv, 8);
            lr[m][r] = lr[m][r] * alpha[m][r] + sv;
          }
        #pragma unroll
        for (int m = 0; m < 2; m++)
          #pragma unroll
          for (int blk = 0; blk < 8; blk++){
            o[m][blk][0] *= alpha[m][0]; o[m][blk][1] *= alpha[m][1];
            o[m][blk][2] *= alpha[m][2]; o[m][blk][3] *= alpha[m][3];
          }
        __builtin_amdgcn_s_waitcnt(0xC07F);   // lgkmcnt(0): own-wave P writes visible
        int nch = (smax >> 1) + 1;
        #pragma unroll
        for (int c2 = 0; c2 < 2; c2++){
          if (c2 < nch){
            short8 pf[2];
            #pragma unroll
            for (int m = 0; m < 2; m++)
              pf[m] = *(const short8*)(PW + (m * 16 + l15) * 72 + c2 * 32 + quad * 8);
            #pragma unroll
            for (int blk = 0; blk < 8; blk++){
              int d = blk * 16 + l15;
              short8 vf = *(const short8*)(VsB + d * 64 + (((c2 * 4 + quad) ^ (l15 & 7)) * 8));
              #pragma unroll
              for (int m = 0; m < 2; m++)
                o[m][blk] = __builtin_amdgcn_mfma_f32_16x16x32_bf16(pf[m], vf, o[m][blk], 0, 0, 0);
            }
          }
        }
      }
    }

    // phase epilogue
    int b = bh >> 4, h = bh & 15;
    #pragma unroll
    for (int m = 0; m < 2; m++){
      float inv[4];
      #pragma unroll
      for (int r = 0; r < 4; r++) inv[r] = 1.0f / lr[m][r];
      #pragma unroll
      for (int blk = 0; blk < 8; blk++){
        int d = h * 128 + blk * 16 + l15;
        #pragma unroll
        for (int r = 0; r < 4; r++){
          int srow = qw + m * 16 + quad * 4 + r;
          O[((size_t)(b * 2048 + srow)) * 2048 + d] = f2bf(o[m][blk][r] * inv[r]);
        }
      }
    }
  }
}

// ---------- launcher ----------
extern "C" void kernel_launch(void* const* d_in, const int* in_sizes, int n_in,
                              void* d_out, int out_size, void* d_ws, size_t ws_size,
                              hipStream_t stream)
{
  const float* x  = (const float*)d_in[0];
  const float* Wq = (const float*)d_in[2];
  const float* bq = (const float*)d_in[3];
  const float* Wk = (const float*)d_in[4];
  const float* bk = (const float*)d_in[5];
  const float* Wv = (const float*)d_in[6];
  const float* bv = (const float*)d_in[7];
  const float* Wo = (const float*)d_in[8];
  const float* bo = (const float*)d_in[9];
  float* out = (float*)d_out;

  char* ws = (char*)d_ws;
  u16* xb   = (u16*)(ws);                    // [4096][2048]
  u16* wcat = (u16*)(ws + 16777216);         // [6144][2048] Wq|Wk|Wv, Wo contiguous after
  u16* wob  = (u16*)(ws + 41943040);         // [2048][2048]
  u16* qws  = (u16*)(ws + 50331648);         // [32][2048][128]
  u16* kws  = (u16*)(ws + 67108864);
  u16* vws  = (u16*)(ws + 83886080);         // [32][128][2048] V^T
  u16* attn = (u16*)(ws + 100663296);        // [4096][2048]

  cvt_all<<<24576, 256, 0, stream>>>(x, Wq, Wk, Wv, Wo, xb, wcat);

  gemm_bt<<<dim3(48, 32), 256, 0, stream>>>(xb, wcat, 0, qws, kws, vws,
                                            bq, bk, bv, nullptr, nullptr);
  flash<<<dim3(8, 32), 256, 0, stream>>>(qws, kws, vws, attn);
  gemm_bt<<<dim3(16, 32), 256, 0, stream>>>(attn, wob, 1, nullptr, nullptr, nullptr,
                                            nullptr, nullptr, nullptr, out, bo);
}

// Round 3
// 412.281 us; speedup vs baseline: 1.3178x; 1.0132x over previous
//
#include <hip/hip_runtime.h>

typedef unsigned short u16;
typedef __attribute__((ext_vector_type(8))) short short8;
typedef __attribute__((ext_vector_type(4))) float f32x4;
typedef __attribute__((ext_vector_type(4))) unsigned short u16x4;

// ---------- bf16 helpers (OCP bf16 = raw upper 16 bits of fp32, RNE) ----------
__device__ __forceinline__ float bf2f(u16 h){
  unsigned u = ((unsigned)h) << 16; float f; __builtin_memcpy(&f, &u, 4); return f;
}
__device__ __forceinline__ u16 f2bf(float f){
  unsigned u; __builtin_memcpy(&u, &f, 4);
  unsigned r = u + 0x7fffu + ((u >> 16) & 1u);
  return (u16)(r >> 16);
}

// ---------- async global->LDS (16B per lane, wave-uniform LDS base) ----------
__device__ __forceinline__ void glds16(const u16* g, u16* l){
  __builtin_amdgcn_global_load_lds(
      (const __attribute__((address_space(1))) unsigned int*)(const void*)g,
      (__attribute__((address_space(3))) unsigned int*)(void*)l, 16, 0, 0);
}

// ---------- fused fp32 -> bf16 conversion: x (8192 blocks) + 4 weights ----------
__global__ __launch_bounds__(256) void cvt_all(const float* __restrict__ x,
    const float* __restrict__ w0, const float* __restrict__ w1,
    const float* __restrict__ w2, const float* __restrict__ w3,
    u16* __restrict__ xb, u16* __restrict__ wb){
  int blk = blockIdx.x;
  const float* src; u16* dst; int i;
  if (blk < 8192){
    src = x; dst = xb; i = blk * 256 + threadIdx.x;
  } else {
    int b2 = blk - 8192;
    int which = b2 >> 12;
    src = (which == 0) ? w0 : (which == 1) ? w1 : (which == 2) ? w2 : w3;
    dst = wb + (size_t)which * 4194304;
    i = (b2 & 4095) * 256 + threadIdx.x;
  }
  float4 f = ((const float4*)src)[i];
  u16x4 o; o.x = f2bf(f.x); o.y = f2bf(f.y); o.z = f2bf(f.z); o.w = f2bf(f.w);
  ((u16x4*)dst)[i] = o;
}

// ---------- GEMM C[M,N] = A[M,K] @ B[N,K]^T  (both bf16, K=2048, BK=64) ----------
// BK=64 (32 MFMA per barrier pair) with register diet to stay under the 128-VGPR
// occupancy cliff (m69: waves/CU halve at 128): 2 staging pointers instead of 8
// (ri-offset is a compile-time +ri*32*K; swizzle k-granule is ri-invariant since
// 32%8==0), and kk=1 LDS read offsets derived via ^32 ((x^4)<<3 == (x<<3)^32).
// __launch_bounds__(256,4) pins the allocator to <=128 VGPR -> 4 blocks/CU.
__global__ __launch_bounds__(256, 4) void gemm_bt(
    const u16* __restrict__ A, const u16* __restrict__ Bm, int mode,
    u16* __restrict__ qws, u16* __restrict__ kws, u16* __restrict__ vws,
    const float* __restrict__ bq, const float* __restrict__ bk, const float* __restrict__ bv,
    float* __restrict__ outf, const float* __restrict__ bo)
{
  const int K = 2048;
  __shared__ __attribute__((aligned(16))) u16 As[128 * 64];   // 16 KB
  __shared__ __attribute__((aligned(16))) u16 Bs[128 * 64];   // 16 KB

  int tid = threadIdx.x, wave = tid >> 6, lane = tid & 63;
  int quad = lane >> 4, l15 = lane & 15;
  int wm = wave >> 1, wn = wave & 1;

  size_t rowA0 = (size_t)blockIdx.y * 128;
  size_t rowB0 = (size_t)blockIdx.x * 128;

  // Staging geometry: LDS granule s (16B) = ri*256 + tid holds global
  // (row = s>>3, k-granule = (s&7) ^ (row&7)). ri*256 is 0 mod 8, and
  // ri*32 rows is 0 mod 8, so both (s&7) and (row&7) are ri-invariant:
  // one base pointer + constant ri*32*K offset suffices.
  int lrow0 = tid >> 3;
  int c0 = (tid & 7) ^ (lrow0 & 7);
  const u16* gA = A  + (rowA0 + lrow0) * K + c0 * 8;
  const u16* gB = Bm + (rowB0 + lrow0) * K + c0 * 8;
  u16* lA = As + (size_t)(wave * 64) * 8;
  u16* lB = Bs + (size_t)(wave * 64) * 8;

  f32x4 acc[4][4];
  #pragma unroll
  for (int i = 0; i < 4; i++)
    #pragma unroll
    for (int j = 0; j < 4; j++) acc[i][j] = f32x4{0.f, 0.f, 0.f, 0.f};

  // Read offsets (elements): fragment (row r, k-granule kg) lives at
  // r*64 + ((kg ^ (r&7))*8). kk=0 -> kg=quad; kk=1 -> kg=4+quad = quad^4,
  // so the kk=1 offset is the kk=0 offset ^ 32.
  int aoff[4], boff[4];
  #pragma unroll
  for (int t = 0; t < 4; t++){
    int ra = wm * 64 + t * 16 + l15;
    aoff[t] = ra * 64 + ((quad ^ (ra & 7)) * 8);
    int rb = wn * 32 + (t >> 1) * 64 + (t & 1) * 16 + l15;
    boff[t] = rb * 64 + ((quad ^ (rb & 7)) * 8);
  }

  for (int k0 = 0; k0 < K; k0 += 64){
    __syncthreads();
    #pragma unroll
    for (int ri = 0; ri < 4; ri++){
      glds16(gA + ri * 65536, lA + ri * 2048);   // ri*32 rows * K elements
      glds16(gB + ri * 65536, lB + ri * 2048);
    }
    gA += 64; gB += 64;
    __syncthreads();
    #pragma unroll
    for (int kk = 0; kk < 2; kk++){
      const int kx = kk * 32;
      short8 af[4], bfr[4];
      #pragma unroll
      for (int t = 0; t < 4; t++){
        af[t]  = *(const short8*)(As + (aoff[t] ^ kx));
        bfr[t] = *(const short8*)(Bs + (boff[t] ^ kx));
      }
      #pragma unroll
      for (int i = 0; i < 4; i++)
        #pragma unroll
        for (int j = 0; j < 4; j++)
          acc[i][j] = __builtin_amdgcn_mfma_f32_16x16x32_bf16(af[i], bfr[j], acc[i][j], 0, 0, 0);
    }
  }

  if (mode == 0){
    int col0 = (int)rowB0;
    int mat = col0 >> 11;                  // 0=Q 1=K 2=V
    int cm  = col0 & 2047;
    const float* bias = (mat == 0) ? bq : (mat == 1) ? bk : bv;
    int b  = (int)(rowA0 >> 11);
    int s0 = (int)(rowA0 & 2047);
    int h  = cm >> 7;
    size_t base = ((size_t)(b * 16 + h)) * 2048 * 128;
    if (mat == 2){
      // V stored TRANSPOSED: [B,H,DK,S]
      #pragma unroll
      for (int j = 0; j < 4; j++){
        int d = wn * 32 + (j >> 1) * 64 + (j & 1) * 16 + l15;
        float bv_ = bias[cm + d];
        #pragma unroll
        for (int i = 0; i < 4; i++){
          int srow = s0 + wm * 64 + i * 16 + quad * 4;
          u16x4 pk;
          #pragma unroll
          for (int r = 0; r < 4; r++) pk[r] = f2bf(acc[i][j][r] + bv_);
          *(u16x4*)(vws + base + (size_t)d * 2048 + srow) = pk;
        }
      }
    } else {
      // Q/K: fused bias + RoPE, pairs (dlow, dlow+64) = (acc[*][jp], acc[*][jp+2])
      u16* dst = (mat == 0) ? qws : kws;
      #pragma unroll
      for (int jp = 0; jp < 2; jp++){
        int dlow = wn * 32 + jp * 16 + l15;          // 0..63
        float bias_lo = bias[cm + dlow];
        float bias_hi = bias[cm + dlow + 64];
        float invf = __expf(-0.14391156831212788f * (float)dlow);
        #pragma unroll
        for (int i = 0; i < 4; i++){
          int srow0 = s0 + wm * 64 + i * 16 + quad * 4;
          #pragma unroll
          for (int r = 0; r < 4; r++){
            float a  = acc[i][jp][r]     + bias_lo;
            float b2 = acc[i][jp + 2][r] + bias_hi;
            float th = (float)(srow0 + r) * invf;
            float sn, cs; __sincosf(th, &sn, &cs);
            size_t ro = base + (size_t)(srow0 + r) * 128;
            dst[ro + dlow]      = f2bf(a * cs - b2 * sn);
            dst[ro + dlow + 64] = f2bf(b2 * cs + a * sn);
          }
        }
      }
    }
  } else {
    int col0 = (int)rowB0;
    #pragma unroll
    for (int j = 0; j < 4; j++){
      int c = col0 + wn * 32 + (j >> 1) * 64 + (j & 1) * 16 + l15;
      float bo_ = bo[c];
      #pragma unroll
      for (int i = 0; i < 4; i++){
        int rg = (int)rowA0 + wm * 64 + i * 16 + quad * 4;
        #pragma unroll
        for (int r = 0; r < 4; r++)
          outf[(size_t)(rg + r) * 2048 + c] = acc[i][j][r] + bo_;
      }
    }
  }
}

// ---------- causal flash attention v2: QBLK=64, 2 blocks/CU ----------
// grid (16, 32 bh); block = 4 waves, each wave owns 16 q-rows. LDS = 32K (K dbuf)
// + 32K (V^T dbuf) + 8K (P, XOR-swizzled) = 73.75 KB <= 80 KB -> 2 blocks/CU,
// 8 waves/CU (was 82 KB -> 1 block -> 1 wave/SIMD, pure latency-bound at
// MfmaUtil 10%). Pairs (pr, 31-pr) -> every block exactly 33 kv-iters of 64.
// P-tile layout row*64 + ((col>>3 ^ (row&7))<<3) + (col&7): reads start at bank
// 4*(chunk ^ (l15&7)) -> full 32-bank spread (was 8-way conflicted pad-72 layout,
// 532K conflicts/dispatch).
__global__ __launch_bounds__(256, 2) void flash(
    const u16* __restrict__ Q, const u16* __restrict__ Km, const u16* __restrict__ VT,
    u16* __restrict__ O)
{
  __shared__ __attribute__((aligned(16))) u16 Ks[2][64 * 128];  // 2x16 KB
  __shared__ __attribute__((aligned(16))) u16 Vs[2][128 * 64];  // 2x16 KB (V^T: [d][kv])
  __shared__ __attribute__((aligned(16))) u16 PL[4 * 16 * 64];  // 8 KB per-wave P
  const float scale = 0.08838834764831845f;   // 1/sqrt(128)

  int bh = blockIdx.y;
  int pr = (int)blockIdx.x;              // 0..15
  int tid = threadIdx.x, wave = tid >> 6, lane = tid & 63;
  int quad = lane >> 4, l15 = lane & 15;

  const u16* Qb = Q  + (size_t)bh * 2048 * 128;
  const u16* Kb = Km + (size_t)bh * 2048 * 128;
  const u16* Vb = VT + (size_t)bh * 2048 * 128;   // [d=128][s=2048]
  u16* PW = PL + wave * (16 * 64);

  // staging lane geometry (tile-relative). r-invariant base: granule
  // s = r*256 + tid; r*256 rows are 0 mod 16 (K) / 0 mod 8 (V), so the XOR'd
  // k-granule is r-invariant and r contributes only a constant address offset.
  int krow0 = tid >> 4;
  const u16* gK0 = Kb + (size_t)krow0 * 128 + ((tid & 15) ^ (krow0 & 15)) * 8;
  int vd0 = tid >> 3;
  const u16* gV0 = Vb + (size_t)vd0 * 2048 + ((tid & 7) ^ (vd0 & 7)) * 8;
  int lOff0 = wave * 512;

  for (int phase = 0; phase < 2; phase++){
    int qtile = phase ? (31 - pr) : pr;
    int qw = qtile * 64 + wave * 16;

    short8 qf[4];
    {
      const u16* qr = Qb + (size_t)(qw + l15) * 128 + quad * 8;
      #pragma unroll
      for (int c = 0; c < 4; c++) qf[c] = *(const short8*)(qr + c * 32);
    }

    float mr[4], lr[4]; f32x4 o[8];
    #pragma unroll
    for (int r = 0; r < 4; r++){ mr[r] = -1e30f; lr[r] = 0.f; }
    #pragma unroll
    for (int blk = 0; blk < 8; blk++) o[blk] = f32x4{0.f, 0.f, 0.f, 0.f};

    int niter = qtile + 1;

    __syncthreads();   // previous phase's reads of Ks/Vs complete before re-staging
    #pragma unroll
    for (int r = 0; r < 4; r++){
      glds16(gK0 + r * 2048,  Ks[0] + lOff0 + r * 2048);
      glds16(gV0 + r * 65536, Vs[0] + lOff0 + r * 2048);
    }

    for (int it = 0; it < niter; it++){
      int k0 = it * 64;
      int buf = it & 1;
      __syncthreads();   // vmcnt(0)+barrier: buf's tile landed; all waves done w/ buf^1
      if (it + 1 < niter){
        int nb = buf ^ 1;
        #pragma unroll
        for (int r = 0; r < 4; r++){
          glds16(gK0 + (size_t)(k0 + 64) * 128 + r * 2048, Ks[nb] + lOff0 + r * 2048);
          glds16(gV0 + (k0 + 64) + r * 65536,              Vs[nb] + lOff0 + r * 2048);
        }
      }
      const u16* KsB = Ks[buf];
      const u16* VsB = Vs[buf];

      // rel = qw+15-k0 >= wave*16+15 >= 0 always within niter
      int rel = qw + 15 - k0;
      int smax = rel >> 4; if (smax > 3) smax = 3;
      float sreg[4][4];
      #pragma unroll
      for (int t = 0; t < 4; t++){
        if (t <= smax){
          short8 kf[4];
          #pragma unroll
          for (int c = 0; c < 4; c++)
            kf[c] = *(const short8*)(KsB + (t * 16 + l15) * 128 + (((c * 4 + quad) ^ l15) * 8));
          f32x4 a = f32x4{0.f, 0.f, 0.f, 0.f};
          #pragma unroll
          for (int c = 0; c < 4; c++)
            a = __builtin_amdgcn_mfma_f32_16x16x32_bf16(qf[c], kf[c], a, 0, 0, 0);
          int kvcol = k0 + t * 16 + l15;
          #pragma unroll
          for (int r = 0; r < 4; r++){
            float v = a[r] * scale;
            int row = qw + quad * 4 + r;
            if (kvcol > row) v = -1e30f;
            sreg[t][r] = v;
          }
        }
      }
      float alpha[4];
      #pragma unroll
      for (int r = 0; r < 4; r++){
        float x = sreg[0][r];
        #pragma unroll
        for (int t = 1; t < 4; t++) if (t <= smax) x = fmaxf(x, sreg[t][r]);
        x = fmaxf(x, __shfl_xor(x, 1));
        x = fmaxf(x, __shfl_xor(x, 2));
        x = fmaxf(x, __shfl_xor(x, 4));
        x = fmaxf(x, __shfl_xor(x, 8));
        float mn = fmaxf(mr[r], x);
        alpha[r] = __expf(mr[r] - mn);
        mr[r] = mn;
      }
      float lsum[4];
      #pragma unroll
      for (int r = 0; r < 4; r++) lsum[r] = 0.f;
      #pragma unroll
      for (int t = 0; t < 4; t++){
        if (t <= smax){
          int chi = t * 2 + (l15 >> 3);
          #pragma unroll
          for (int r = 0; r < 4; r++){
            float p = __expf(sreg[t][r] - mr[r]);
            lsum[r] += p;
            int row = quad * 4 + r;
            PW[row * 64 + ((chi ^ (row & 7)) << 3) + (l15 & 7)] = f2bf(p);
          }
        }
      }
      if (!(smax & 1)){
        int chi = (smax + 1) * 2 + (l15 >> 3);
        #pragma unroll
        for (int r = 0; r < 4; r++){
          int row = quad * 4 + r;
          PW[row * 64 + ((chi ^ (row & 7)) << 3) + (l15 & 7)] = 0;
        }
      }
      #pragma unroll
      for (int r = 0; r < 4; r++){
        float sv = lsum[r];
        sv += __shfl_xor(sv, 1); sv += __shfl_xor(sv, 2);
        sv += __shfl_xor(sv, 4); sv += __shfl_xor(sv, 8);
        lr[r] = lr[r] * alpha[r] + sv;
      }
      #pragma unroll
      for (int blk = 0; blk < 8; blk++){
        o[blk][0] *= alpha[0]; o[blk][1] *= alpha[1];
        o[blk][2] *= alpha[2]; o[blk][3] *= alpha[3];
      }
      __builtin_amdgcn_s_waitcnt(0xC07F);   // lgkmcnt(0): own-wave P writes visible
      int nch = (smax >> 1) + 1;
      #pragma unroll
      for (int c2 = 0; c2 < 2; c2++){
        if (c2 < nch){
          short8 pf = *(const short8*)(PW + l15 * 64 + (((c2 * 4 + quad) ^ (l15 & 7)) << 3));
          #pragma unroll
          for (int blk = 0; blk < 8; blk++){
            int d = blk * 16 + l15;
            short8 vf = *(const short8*)(VsB + d * 64 + (((c2 * 4 + quad) ^ (l15 & 7)) * 8));
            o[blk] = __builtin_amdgcn_mfma_f32_16x16x32_bf16(pf, vf, o[blk], 0, 0, 0);
          }
        }
      }
    }

    // phase epilogue
    int b = bh >> 4, h = bh & 15;
    float inv[4];
    #pragma unroll
    for (int r = 0; r < 4; r++) inv[r] = 1.0f / lr[r];
    #pragma unroll
    for (int blk = 0; blk < 8; blk++){
      int d = h * 128 + blk * 16 + l15;
      #pragma unroll
      for (int r = 0; r < 4; r++){
        int srow = qw + quad * 4 + r;
        O[((size_t)(b * 2048 + srow)) * 2048 + d] = f2bf(o[blk][r] * inv[r]);
      }
    }
  }
}

// ---------- launcher ----------
extern "C" void kernel_launch(void* const* d_in, const int* in_sizes, int n_in,
                              void* d_out, int out_size, void* d_ws, size_t ws_size,
                              hipStream_t stream)
{
  const float* x  = (const float*)d_in[0];
  const float* Wq = (const float*)d_in[2];
  const float* bq = (const float*)d_in[3];
  const float* Wk = (const float*)d_in[4];
  const float* bk = (const float*)d_in[5];
  const float* Wv = (const float*)d_in[6];
  const float* bv = (const float*)d_in[7];
  const float* Wo = (const float*)d_in[8];
  const float* bo = (const float*)d_in[9];
  float* out = (float*)d_out;

  char* ws = (char*)d_ws;
  u16* xb   = (u16*)(ws);                    // [4096][2048]
  u16* wcat = (u16*)(ws + 16777216);         // [6144][2048] Wq|Wk|Wv, Wo contiguous after
  u16* wob  = (u16*)(ws + 41943040);         // [2048][2048]
  u16* qws  = (u16*)(ws + 50331648);         // [32][2048][128]
  u16* kws  = (u16*)(ws + 67108864);
  u16* vws  = (u16*)(ws + 83886080);         // [32][128][2048] V^T
  u16* attn = (u16*)(ws + 100663296);        // [4096][2048]

  cvt_all<<<24576, 256, 0, stream>>>(x, Wq, Wk, Wv, Wo, xb, wcat);

  gemm_bt<<<dim3(48, 32), 256, 0, stream>>>(xb, wcat, 0, qws, kws, vws,
                                            bq, bk, bv, nullptr, nullptr);
  flash<<<dim3(16, 32), 256, 0, stream>>>(qws, kws, vws, attn);
  gemm_bt<<<dim3(16, 32), 256, 0, stream>>>(attn, wob, 1, nullptr, nullptr, nullptr,
                                            nullptr, nullptr, nullptr, out, bo);
}

// Round 4
// 404.599 us; speedup vs baseline: 1.3428x; 1.0190x over previous
//
#include <hip/hip_runtime.h>

typedef unsigned short u16;
typedef __attribute__((ext_vector_type(8))) short short8;
typedef __attribute__((ext_vector_type(4))) float f32x4;
typedef __attribute__((ext_vector_type(4))) unsigned short u16x4;

// ---------- bf16 helpers (OCP bf16 = raw upper 16 bits of fp32, RNE) ----------
__device__ __forceinline__ float bf2f(u16 h){
  unsigned u = ((unsigned)h) << 16; float f; __builtin_memcpy(&f, &u, 4); return f;
}
__device__ __forceinline__ u16 f2bf(float f){
  unsigned u; __builtin_memcpy(&u, &f, 4);
  unsigned r = u + 0x7fffu + ((u >> 16) & 1u);
  return (u16)(r >> 16);
}

// ---------- async global->LDS (16B per lane, wave-uniform LDS base) ----------
__device__ __forceinline__ void glds16(const u16* g, u16* l){
  __builtin_amdgcn_global_load_lds(
      (const __attribute__((address_space(1))) unsigned int*)(const void*)g,
      (__attribute__((address_space(3))) unsigned int*)(void*)l, 16, 0, 0);
}

// ---------- fused fp32 -> bf16 conversion: x (8192 blocks) + 4 weights ----------
__global__ __launch_bounds__(256) void cvt_all(const float* __restrict__ x,
    const float* __restrict__ w0, const float* __restrict__ w1,
    const float* __restrict__ w2, const float* __restrict__ w3,
    u16* __restrict__ xb, u16* __restrict__ wb){
  int blk = blockIdx.x;
  const float* src; u16* dst; int i;
  if (blk < 8192){
    src = x; dst = xb; i = blk * 256 + threadIdx.x;
  } else {
    int b2 = blk - 8192;
    int which = b2 >> 12;
    src = (which == 0) ? w0 : (which == 1) ? w1 : (which == 2) ? w2 : w3;
    dst = wb + (size_t)which * 4194304;
    i = (b2 & 4095) * 256 + threadIdx.x;
  }
  float4 f = ((const float4*)src)[i];
  u16x4 o; o.x = f2bf(f.x); o.y = f2bf(f.y); o.z = f2bf(f.z); o.w = f2bf(f.w);
  ((u16x4*)dst)[i] = o;
}

// ---------- GEMM C[M,N] = A[M,K] @ B[N,K]^T  (both bf16, K=2048, BK=64) ----------
// BK=64 (32 MFMA per barrier pair) with register diet to stay under the 128-VGPR
// occupancy cliff (m69: waves/CU halve at 128): 2 staging pointers instead of 8
// (ri-offset is a compile-time +ri*32*K; swizzle k-granule is ri-invariant since
// 32%8==0), and kk=1 LDS read offsets derived via ^32 ((x^4)<<3 == (x<<3)^32).
// __launch_bounds__(256,4) pins the allocator to <=128 VGPR -> 4 blocks/CU.
__global__ __launch_bounds__(256, 4) void gemm_bt(
    const u16* __restrict__ A, const u16* __restrict__ Bm, int mode,
    u16* __restrict__ qws, u16* __restrict__ kws, u16* __restrict__ vws,
    const float* __restrict__ bq, const float* __restrict__ bk, const float* __restrict__ bv,
    float* __restrict__ outf, const float* __restrict__ bo)
{
  const int K = 2048;
  __shared__ __attribute__((aligned(16))) u16 As[128 * 64];   // 16 KB
  __shared__ __attribute__((aligned(16))) u16 Bs[128 * 64];   // 16 KB

  int tid = threadIdx.x, wave = tid >> 6, lane = tid & 63;
  int quad = lane >> 4, l15 = lane & 15;
  int wm = wave >> 1, wn = wave & 1;

  size_t rowA0 = (size_t)blockIdx.y * 128;
  size_t rowB0 = (size_t)blockIdx.x * 128;

  // Staging geometry: LDS granule s (16B) = ri*256 + tid holds global
  // (row = s>>3, k-granule = (s&7) ^ (row&7)). ri*256 is 0 mod 8, and
  // ri*32 rows is 0 mod 8, so both (s&7) and (row&7) are ri-invariant:
  // one base pointer + constant ri*32*K offset suffices.
  int lrow0 = tid >> 3;
  int c0 = (tid & 7) ^ (lrow0 & 7);
  const u16* gA = A  + (rowA0 + lrow0) * K + c0 * 8;
  const u16* gB = Bm + (rowB0 + lrow0) * K + c0 * 8;
  u16* lA = As + (size_t)(wave * 64) * 8;
  u16* lB = Bs + (size_t)(wave * 64) * 8;

  f32x4 acc[4][4];
  #pragma unroll
  for (int i = 0; i < 4; i++)
    #pragma unroll
    for (int j = 0; j < 4; j++) acc[i][j] = f32x4{0.f, 0.f, 0.f, 0.f};

  // Read offsets (elements): fragment (row r, k-granule kg) lives at
  // r*64 + ((kg ^ (r&7))*8). kk=0 -> kg=quad; kk=1 -> kg=4+quad = quad^4,
  // so the kk=1 offset is the kk=0 offset ^ 32.
  int aoff[4], boff[4];
  #pragma unroll
  for (int t = 0; t < 4; t++){
    int ra = wm * 64 + t * 16 + l15;
    aoff[t] = ra * 64 + ((quad ^ (ra & 7)) * 8);
    int rb = wn * 32 + (t >> 1) * 64 + (t & 1) * 16 + l15;
    boff[t] = rb * 64 + ((quad ^ (rb & 7)) * 8);
  }

  for (int k0 = 0; k0 < K; k0 += 64){
    __syncthreads();
    #pragma unroll
    for (int ri = 0; ri < 4; ri++){
      glds16(gA + ri * 65536, lA + ri * 2048);   // ri*32 rows * K elements
      glds16(gB + ri * 65536, lB + ri * 2048);
    }
    gA += 64; gB += 64;
    __syncthreads();
    #pragma unroll
    for (int kk = 0; kk < 2; kk++){
      const int kx = kk * 32;
      short8 af[4], bfr[4];
      #pragma unroll
      for (int t = 0; t < 4; t++){
        af[t]  = *(const short8*)(As + (aoff[t] ^ kx));
        bfr[t] = *(const short8*)(Bs + (boff[t] ^ kx));
      }
      #pragma unroll
      for (int i = 0; i < 4; i++)
        #pragma unroll
        for (int j = 0; j < 4; j++)
          acc[i][j] = __builtin_amdgcn_mfma_f32_16x16x32_bf16(af[i], bfr[j], acc[i][j], 0, 0, 0);
    }
  }

  if (mode == 0){
    int col0 = (int)rowB0;
    int mat = col0 >> 11;                  // 0=Q 1=K 2=V
    int cm  = col0 & 2047;
    const float* bias = (mat == 0) ? bq : (mat == 1) ? bk : bv;
    int b  = (int)(rowA0 >> 11);
    int s0 = (int)(rowA0 & 2047);
    int h  = cm >> 7;
    size_t base = ((size_t)(b * 16 + h)) * 2048 * 128;
    if (mat == 2){
      // V stored TRANSPOSED: [B,H,DK,S]
      #pragma unroll
      for (int j = 0; j < 4; j++){
        int d = wn * 32 + (j >> 1) * 64 + (j & 1) * 16 + l15;
        float bv_ = bias[cm + d];
        #pragma unroll
        for (int i = 0; i < 4; i++){
          int srow = s0 + wm * 64 + i * 16 + quad * 4;
          u16x4 pk;
          #pragma unroll
          for (int r = 0; r < 4; r++) pk[r] = f2bf(acc[i][j][r] + bv_);
          *(u16x4*)(vws + base + (size_t)d * 2048 + srow) = pk;
        }
      }
    } else {
      // Q/K: fused bias + RoPE, pairs (dlow, dlow+64) = (acc[*][jp], acc[*][jp+2])
      u16* dst = (mat == 0) ? qws : kws;
      #pragma unroll
      for (int jp = 0; jp < 2; jp++){
        int dlow = wn * 32 + jp * 16 + l15;          // 0..63
        float bias_lo = bias[cm + dlow];
        float bias_hi = bias[cm + dlow + 64];
        float invf = __expf(-0.14391156831212788f * (float)dlow);
        #pragma unroll
        for (int i = 0; i < 4; i++){
          int srow0 = s0 + wm * 64 + i * 16 + quad * 4;
          #pragma unroll
          for (int r = 0; r < 4; r++){
            float a  = acc[i][jp][r]     + bias_lo;
            float b2 = acc[i][jp + 2][r] + bias_hi;
            float th = (float)(srow0 + r) * invf;
            float sn, cs; __sincosf(th, &sn, &cs);
            size_t ro = base + (size_t)(srow0 + r) * 128;
            dst[ro + dlow]      = f2bf(a * cs - b2 * sn);
            dst[ro + dlow + 64] = f2bf(b2 * cs + a * sn);
          }
        }
      }
    }
  } else {
    int col0 = (int)rowB0;
    #pragma unroll
    for (int j = 0; j < 4; j++){
      int c = col0 + wn * 32 + (j >> 1) * 64 + (j & 1) * 16 + l15;
      float bo_ = bo[c];
      #pragma unroll
      for (int i = 0; i < 4; i++){
        int rg = (int)rowA0 + wm * 64 + i * 16 + quad * 4;
        #pragma unroll
        for (int r = 0; r < 4; r++)
          outf[(size_t)(rg + r) * 2048 + c] = acc[i][j][r] + bo_;
      }
    }
  }
}

// ---------- causal flash attention v3: QBLK=64, 2 blocks/CU, XCD-local KV ----------
// 512 blocks remapped so all 16 pr-blocks of a head land on ONE XCD (4 heads/XCD,
// KV working set 4 MB = L2 size; was 32 heads sprayed across XCDs -> 254 MB HBM
// re-fetch at 2.4 TB/s). Assumes round-robin linear-id -> XCD dispatch (T1/m157).
// defer-max (T13, THR=8): skip alpha-exp + o-rescale + mr update when the tile
// max grew by <= 8 (almost every iter on normal-ish scores); P bounded by e^8,
// fine in bf16/f32.
__global__ __launch_bounds__(256, 2) void flash(
    const u16* __restrict__ Q, const u16* __restrict__ Km, const u16* __restrict__ VT,
    u16* __restrict__ O)
{
  __shared__ __attribute__((aligned(16))) u16 Ks[2][64 * 128];  // 2x16 KB
  __shared__ __attribute__((aligned(16))) u16 Vs[2][128 * 64];  // 2x16 KB (V^T: [d][kv])
  __shared__ __attribute__((aligned(16))) u16 PL[4 * 16 * 64];  // 8 KB per-wave P
  const float scale = 0.08838834764831845f;   // 1/sqrt(128)

  // XCD-chunked swizzle: id -> (xcd = id&7, k = id>>3); head bh = xcd + 8*(k>>4),
  // pr = k&15. Bijective over 512; each XCD serves 4 heads' full KV.
  int id = (int)(blockIdx.x + (blockIdx.y << 4));
  int xcd = id & 7;
  int kk_ = id >> 3;                     // 0..63
  int bh = xcd + ((kk_ >> 4) << 3);      // {xcd, xcd+8, xcd+16, xcd+24}
  int pr = kk_ & 15;                     // 0..15
  int tid = threadIdx.x, wave = tid >> 6, lane = tid & 63;
  int quad = lane >> 4, l15 = lane & 15;

  const u16* Qb = Q  + (size_t)bh * 2048 * 128;
  const u16* Kb = Km + (size_t)bh * 2048 * 128;
  const u16* Vb = VT + (size_t)bh * 2048 * 128;   // [d=128][s=2048]
  u16* PW = PL + wave * (16 * 64);

  // staging lane geometry (tile-relative). r-invariant base: granule
  // s = r*256 + tid; r*256 rows are 0 mod 16 (K) / 0 mod 8 (V), so the XOR'd
  // k-granule is r-invariant and r contributes only a constant address offset.
  int krow0 = tid >> 4;
  const u16* gK0 = Kb + (size_t)krow0 * 128 + ((tid & 15) ^ (krow0 & 15)) * 8;
  int vd0 = tid >> 3;
  const u16* gV0 = Vb + (size_t)vd0 * 2048 + ((tid & 7) ^ (vd0 & 7)) * 8;
  int lOff0 = wave * 512;

  for (int phase = 0; phase < 2; phase++){
    int qtile = phase ? (31 - pr) : pr;
    int qw = qtile * 64 + wave * 16;

    short8 qf[4];
    {
      const u16* qr = Qb + (size_t)(qw + l15) * 128 + quad * 8;
      #pragma unroll
      for (int c = 0; c < 4; c++) qf[c] = *(const short8*)(qr + c * 32);
    }

    float mr[4], lr[4]; f32x4 o[8];
    #pragma unroll
    for (int r = 0; r < 4; r++){ mr[r] = -1e30f; lr[r] = 0.f; }
    #pragma unroll
    for (int blk = 0; blk < 8; blk++) o[blk] = f32x4{0.f, 0.f, 0.f, 0.f};

    int niter = qtile + 1;

    __syncthreads();   // previous phase's reads of Ks/Vs complete before re-staging
    #pragma unroll
    for (int r = 0; r < 4; r++){
      glds16(gK0 + r * 2048,  Ks[0] + lOff0 + r * 2048);
      glds16(gV0 + r * 65536, Vs[0] + lOff0 + r * 2048);
    }

    for (int it = 0; it < niter; it++){
      int k0 = it * 64;
      int buf = it & 1;
      __syncthreads();   // vmcnt(0)+barrier: buf's tile landed; all waves done w/ buf^1
      if (it + 1 < niter){
        int nb = buf ^ 1;
        #pragma unroll
        for (int r = 0; r < 4; r++){
          glds16(gK0 + (size_t)(k0 + 64) * 128 + r * 2048, Ks[nb] + lOff0 + r * 2048);
          glds16(gV0 + (k0 + 64) + r * 65536,              Vs[nb] + lOff0 + r * 2048);
        }
      }
      const u16* KsB = Ks[buf];
      const u16* VsB = Vs[buf];

      // rel = qw+15-k0 >= wave*16+15 >= 0 always within niter
      int rel = qw + 15 - k0;
      int smax = rel >> 4; if (smax > 3) smax = 3;
      float sreg[4][4];
      #pragma unroll
      for (int t = 0; t < 4; t++){
        if (t <= smax){
          short8 kf[4];
          #pragma unroll
          for (int c = 0; c < 4; c++)
            kf[c] = *(const short8*)(KsB + (t * 16 + l15) * 128 + (((c * 4 + quad) ^ l15) * 8));
          f32x4 a = f32x4{0.f, 0.f, 0.f, 0.f};
          #pragma unroll
          for (int c = 0; c < 4; c++)
            a = __builtin_amdgcn_mfma_f32_16x16x32_bf16(qf[c], kf[c], a, 0, 0, 0);
          int kvcol = k0 + t * 16 + l15;
          #pragma unroll
          for (int r = 0; r < 4; r++){
            float v = a[r] * scale;
            int row = qw + quad * 4 + r;
            if (kvcol > row) v = -1e30f;
            sreg[t][r] = v;
          }
        }
      }
      // tile max (uniform within each 16-lane row group after the reduce)
      float px[4];
      #pragma unroll
      for (int r = 0; r < 4; r++){
        float x = sreg[0][r];
        #pragma unroll
        for (int t = 1; t < 4; t++) if (t <= smax) x = fmaxf(x, sreg[t][r]);
        x = fmaxf(x, __shfl_xor(x, 1));
        x = fmaxf(x, __shfl_xor(x, 2));
        x = fmaxf(x, __shfl_xor(x, 4));
        x = fmaxf(x, __shfl_xor(x, 8));
        px[r] = x;
      }
      // defer-max: if no row grew its max by > 8, keep old mr (alpha == 1 path)
      float g01 = fmaxf(px[0] - mr[0], px[1] - mr[1]);
      float g23 = fmaxf(px[2] - mr[2], px[3] - mr[3]);
      int noresc = __all(fmaxf(g01, g23) <= 8.0f);
      float alpha[4];
      if (!noresc){
        #pragma unroll
        for (int r = 0; r < 4; r++){
          float mn = fmaxf(mr[r], px[r]);
          alpha[r] = __expf(mr[r] - mn);
          mr[r] = mn;
        }
      }
      float lsum[4];
      #pragma unroll
      for (int r = 0; r < 4; r++) lsum[r] = 0.f;
      #pragma unroll
      for (int t = 0; t < 4; t++){
        if (t <= smax){
          int chi = t * 2 + (l15 >> 3);
          #pragma unroll
          for (int r = 0; r < 4; r++){
            float p = __expf(sreg[t][r] - mr[r]);
            lsum[r] += p;
            int row = quad * 4 + r;
            PW[row * 64 + ((chi ^ (row & 7)) << 3) + (l15 & 7)] = f2bf(p);
          }
        }
      }
      if (!(smax & 1)){
        int chi = (smax + 1) * 2 + (l15 >> 3);
        #pragma unroll
        for (int r = 0; r < 4; r++){
          int row = quad * 4 + r;
          PW[row * 64 + ((chi ^ (row & 7)) << 3) + (l15 & 7)] = 0;
        }
      }
      #pragma unroll
      for (int r = 0; r < 4; r++){
        float sv = lsum[r];
        sv += __shfl_xor(sv, 1); sv += __shfl_xor(sv, 2);
        sv += __shfl_xor(sv, 4); sv += __shfl_xor(sv, 8);
        lr[r] = noresc ? (lr[r] + sv) : (lr[r] * alpha[r] + sv);
      }
      if (!noresc){
        #pragma unroll
        for (int blk = 0; blk < 8; blk++){
          o[blk][0] *= alpha[0]; o[blk][1] *= alpha[1];
          o[blk][2] *= alpha[2]; o[blk][3] *= alpha[3];
        }
      }
      __builtin_amdgcn_s_waitcnt(0xC07F);   // lgkmcnt(0): own-wave P writes visible
      int nch = (smax >> 1) + 1;
      #pragma unroll
      for (int c2 = 0; c2 < 2; c2++){
        if (c2 < nch){
          short8 pf = *(const short8*)(PW + l15 * 64 + (((c2 * 4 + quad) ^ (l15 & 7)) << 3));
          #pragma unroll
          for (int blk = 0; blk < 8; blk++){
            int d = blk * 16 + l15;
            short8 vf = *(const short8*)(VsB + d * 64 + (((c2 * 4 + quad) ^ (l15 & 7)) * 8));
            o[blk] = __builtin_amdgcn_mfma_f32_16x16x32_bf16(pf, vf, o[blk], 0, 0, 0);
          }
        }
      }
    }

    // phase epilogue
    int b = bh >> 4, h = bh & 15;
    float inv[4];
    #pragma unroll
    for (int r = 0; r < 4; r++) inv[r] = 1.0f / lr[r];
    #pragma unroll
    for (int blk = 0; blk < 8; blk++){
      int d = h * 128 + blk * 16 + l15;
      #pragma unroll
      for (int r = 0; r < 4; r++){
        int srow = qw + quad * 4 + r;
        O[((size_t)(b * 2048 + srow)) * 2048 + d] = f2bf(o[blk][r] * inv[r]);
      }
    }
  }
}

// ---------- launcher ----------
extern "C" void kernel_launch(void* const* d_in, const int* in_sizes, int n_in,
                              void* d_out, int out_size, void* d_ws, size_t ws_size,
                              hipStream_t stream)
{
  const float* x  = (const float*)d_in[0];
  const float* Wq = (const float*)d_in[2];
  const float* bq = (const float*)d_in[3];
  const float* Wk = (const float*)d_in[4];
  const float* bk = (const float*)d_in[5];
  const float* Wv = (const float*)d_in[6];
  const float* bv = (const float*)d_in[7];
  const float* Wo = (const float*)d_in[8];
  const float* bo = (const float*)d_in[9];
  float* out = (float*)d_out;

  char* ws = (char*)d_ws;
  u16* xb   = (u16*)(ws);                    // [4096][2048]
  u16* wcat = (u16*)(ws + 16777216);         // [6144][2048] Wq|Wk|Wv, Wo contiguous after
  u16* wob  = (u16*)(ws + 41943040);         // [2048][2048]
  u16* qws  = (u16*)(ws + 50331648);         // [32][2048][128]
  u16* kws  = (u16*)(ws + 67108864);
  u16* vws  = (u16*)(ws + 83886080);         // [32][128][2048] V^T
  u16* attn = (u16*)(ws + 100663296);        // [4096][2048]

  cvt_all<<<24576, 256, 0, stream>>>(x, Wq, Wk, Wv, Wo, xb, wcat);

  gemm_bt<<<dim3(48, 32), 256, 0, stream>>>(xb, wcat, 0, qws, kws, vws,
                                            bq, bk, bv, nullptr, nullptr);
  flash<<<dim3(16, 32), 256, 0, stream>>>(qws, kws, vws, attn);
  gemm_bt<<<dim3(16, 32), 256, 0, stream>>>(attn, wob, 1, nullptr, nullptr, nullptr,
                                            nullptr, nullptr, nullptr, out, bo);
}